// Round 3
// baseline (95.103 us; speedup 1.0000x reference)
//
#include <hip/hip_runtime.h>

// DistributedMemory forward:
//   inputs[b,:] = P[doc_ids[b],:] + sum_c W[context_ids[b,c],:]      [B,128]
//   out[b,s]    = dot(inputs[b,:], outputs[:, sample_ids[b,s]])      [B,S]
// B=16384, C=8, S=10, D=128, N_WORDS=100000, N_DOCS=1e6. All f32.
//
// R2 -> R3: the explicit transpose cost a 51MB write + 84MB re-read purely
// to fix coalescing. Fused version: bin samples by 64-word chunk, then one
// block per chunk streams its 128x64 slab of `outs` (coalesced, read once,
// 51.2MB total) into LDS and answers its ~105 samples from LDS.
// Kernels: A = build inputs[B,128] (+zero bin counts), B = bin samples,
// E = stream slab + dot. ws: inputs 8.4MB | counts 6KB | list 3.2MB.

#define VEC_DIM   128
#define NW        100000
#define CTX       8
#define NSAMP     10
#define WB        64
#define NCHUNK    ((NW + WB - 1) / WB)   // 1563
#define CAP       512
#define TSTRIDE   (WB + 1)               // 65 floats: bank-conflict-free

// ---------------- A: inputs[b] = P[doc] + sum W[ctx]; also zero counts ----
__global__ __launch_bounds__(256) void build_inputs_kernel(
    const int* __restrict__ doc_ids,
    const int* __restrict__ context_ids,
    const float* __restrict__ P,       // [N_DOCS,128]
    const float* __restrict__ W,       // [NW,128]
    float* __restrict__ inputs,        // [B,128] (ws)
    int* __restrict__ counts)          // [NCHUNK] (ws)
{
    if (blockIdx.x == 0) {
        for (int i = threadIdx.x; i < NCHUNK; i += 256) counts[i] = 0;
    }
    const int t = threadIdx.x & 31;                      // 32 lanes per b
    const int b = blockIdx.x * 8 + (threadIdx.x >> 5);

    const float4* __restrict__ P4 = (const float4*)P;
    const float4* __restrict__ W4 = (const float4*)W;

    float4 v = P4[(long)doc_ids[b] * 32 + t];
    #pragma unroll
    for (int c = 0; c < CTX; ++c) {
        float4 w4 = W4[(long)context_ids[b * CTX + c] * 32 + t];
        v.x += w4.x; v.y += w4.y; v.z += w4.z; v.w += w4.w;
    }
    ((float4*)inputs)[b * 32 + t] = v;
}

// ---------------- B: bin samples by word-chunk ----------------------------
__global__ __launch_bounds__(256) void bin_kernel(
    const int* __restrict__ sample_ids,   // [B*S]
    int* __restrict__ counts,
    int* __restrict__ list)               // [NCHUNK][CAP]
{
    const int p = blockIdx.x * 256 + threadIdx.x;   // sample index < 163840
    const int w = sample_ids[p];
    const int c = w >> 6;                           // WB = 64
    const int slot = atomicAdd(&counts[c], 1);
    if (slot < CAP)
        list[c * CAP + slot] = ((w & (WB - 1)) << 18) | p;   // p < 2^18
}

// ---------------- E: stream 128xWB slab to LDS, dot its samples -----------
__global__ __launch_bounds__(256) void chunk_dot_kernel(
    const float* __restrict__ outs,     // [128, NW]
    const float* __restrict__ inputs,   // [B,128]
    const int* __restrict__ counts,
    const int* __restrict__ list,
    float* __restrict__ out)            // [B*S]
{
    __shared__ float tile[VEC_DIM * TSTRIDE];   // 33,280 B
    const int c  = blockIdx.x;
    const int w0 = c * WB;
    const int tid = threadIdx.x;

    // stream slab: 128 rows x 16 float4 = 2048 f4, 8 per thread, coalesced
    #pragma unroll
    for (int i = 0; i < 8; ++i) {
        const int f4i = i * 256 + tid;      // 0..2047
        const int d   = f4i >> 4;           // row
        const int u   = f4i & 15;           // f4 slot in row
        const int w   = w0 + 4 * u;
        float4 val = make_float4(0.f, 0.f, 0.f, 0.f);
        if (w + 4 <= NW)                    // tail chunk guard (NW%4==0)
            val = *(const float4*)&outs[(long)d * NW + w];
        float* dst = &tile[d * TSTRIDE + 4 * u];
        dst[0] = val.x; dst[1] = val.y; dst[2] = val.z; dst[3] = val.w;
    }
    __syncthreads();

    const int cnt  = min(counts[c], CAP);
    const int wave = tid >> 6;
    const int lane = tid & 63;
    const float2* __restrict__ in2 = (const float2*)inputs;

    for (int i = wave; i < cnt; i += 4) {
        const int e = list[c * CAP + i];
        const int p = e & 0x3FFFF;
        const int j = e >> 18;
        const unsigned b = (unsigned)p / (unsigned)NSAMP;
        const float2 vin = in2[b * 64 + lane];          // 512B row, L2/L3-hot
        // lanes own dims {2*lane, 2*lane+1}; banks (2*lane+k+j)%32: 2-way=free
        const float o0 = tile[(2 * lane)     * TSTRIDE + j];
        const float o1 = tile[(2 * lane + 1) * TSTRIDE + j];
        float acc = vin.x * o0 + vin.y * o1;
        #pragma unroll
        for (int off = 1; off < 64; off <<= 1)
            acc += __shfl_xor(acc, off, 64);
        if (lane == 0) out[p] = acc;
    }
}

// ---------------- fallback (tiny ws): direct strided gather ---------------
__global__ __launch_bounds__(128) void dm_fwd_direct(
    const int* __restrict__ doc_ids,
    const int* __restrict__ context_ids,
    const int* __restrict__ sample_ids,
    const float* __restrict__ P,
    const float* __restrict__ W,
    const float* __restrict__ outs,
    float* __restrict__ out)
{
    const int b = blockIdx.x;
    const int d = threadIdx.x;
    const int lane = d & 63;
    const int wave = d >> 6;

    float v = P[(long)doc_ids[b] * VEC_DIM + d];
    #pragma unroll
    for (int c = 0; c < CTX; ++c)
        v += W[(long)context_ids[b * CTX + c] * VEC_DIM + d];

    __shared__ float partial[2 * NSAMP];
    #pragma unroll
    for (int s = 0; s < NSAMP; ++s) {
        const int w = sample_ids[b * NSAMP + s];
        float p = v * outs[(long)d * NW + w];
        #pragma unroll
        for (int off = 32; off > 0; off >>= 1)
            p += __shfl_down(p, off, 64);
        if (lane == 0) partial[wave * NSAMP + s] = p;
    }
    __syncthreads();
    if (d < NSAMP) out[b * NSAMP + d] = partial[d] + partial[NSAMP + d];
}

extern "C" void kernel_launch(void* const* d_in, const int* in_sizes, int n_in,
                              void* d_out, int out_size, void* d_ws, size_t ws_size,
                              hipStream_t stream) {
    const int*   doc_ids     = (const int*)d_in[0];
    const int*   context_ids = (const int*)d_in[1];
    const int*   sample_ids  = (const int*)d_in[2];
    const float* P           = (const float*)d_in[3];
    const float* W           = (const float*)d_in[4];
    const float* outs        = (const float*)d_in[5];
    float*       out         = (float*)d_out;

    const int B = in_sizes[0];          // 16384
    const int n_samples = B * NSAMP;    // 163840

    // ws layout (256B-aligned offsets)
    const size_t off_inputs = 0;
    const size_t sz_inputs  = (size_t)B * VEC_DIM * sizeof(float);        // 8,388,608
    const size_t off_counts = off_inputs + sz_inputs;
    const size_t sz_counts  = 8192;                                        // NCHUNK*4 padded
    const size_t off_list   = off_counts + sz_counts;
    const size_t sz_list    = (size_t)NCHUNK * CAP * sizeof(int);          // 3,201,024
    const size_t needed     = off_list + sz_list;

    if (ws_size >= needed) {
        float* inputs = (float*)((char*)d_ws + off_inputs);
        int*   counts = (int*)  ((char*)d_ws + off_counts);
        int*   list   = (int*)  ((char*)d_ws + off_list);

        build_inputs_kernel<<<B / 8, 256, 0, stream>>>(
            doc_ids, context_ids, P, W, inputs, counts);
        bin_kernel<<<n_samples / 256, 256, 0, stream>>>(
            sample_ids, counts, list);
        chunk_dot_kernel<<<NCHUNK, 256, 0, stream>>>(
            outs, inputs, counts, list, out);
    } else {
        dm_fwd_direct<<<B, 128, 0, stream>>>(doc_ids, context_ids, sample_ids,
                                             P, W, outs, out);
    }
}

// Round 4
// 63.529 us; speedup vs baseline: 1.4970x; 1.4970x over previous
//
#include <hip/hip_runtime.h>

// DistributedMemory forward:
//   inputs[b,:] = P[doc_ids[b],:] + sum_c W[context_ids[b,c],:]      [B,128]
//   out[b,s]    = dot(inputs[b,:], outputs[:, sample_ids[b,s]])      [B,S]
// B=16384, C=8, S=10, D=128, N_WORDS=100000, N_DOCS=1e6. All f32.
//
// R3 -> R4: binned structure kept (outs read exactly once, no transpose
// round-trip) but the serve phase is rebuilt for throughput:
//  - slab stored transposed [w][d] (stride 132 floats, 16B-aligned)
//  - sample input-rows staged into LDS cooperatively (coalesced 128B segs)
//  - 4 threads per sample, 8x float4 LDS reads each, only 2 shfl steps
// Kernels: memset counts, A build inputs, B bin, E chunk-serve.

#define VEC_DIM 128
#define NW      100000
#define CTX     8
#define NSAMP   10
#define WB      32
#define NCHUNK  (NW / WB)        // 3125 exactly
#define CAP     256
#define TS      132              // padded row stride in floats (528B, 16B-aligned)

// ---------------- A: inputs[b] = P[doc] + sum W[ctx] ----------------------
__global__ __launch_bounds__(256) void build_inputs_kernel(
    const int* __restrict__ doc_ids,
    const int* __restrict__ context_ids,
    const float* __restrict__ P,
    const float* __restrict__ W,
    float* __restrict__ inputs)
{
    const int t = threadIdx.x & 31;                      // 32 lanes per b
    const int b = blockIdx.x * 8 + (threadIdx.x >> 5);

    const float4* __restrict__ P4 = (const float4*)P;
    const float4* __restrict__ W4 = (const float4*)W;

    float4 v = P4[(long)doc_ids[b] * 32 + t];
    #pragma unroll
    for (int c = 0; c < CTX; ++c) {
        float4 w4 = W4[(long)context_ids[b * CTX + c] * 32 + t];
        v.x += w4.x; v.y += w4.y; v.z += w4.z; v.w += w4.w;
    }
    ((float4*)inputs)[b * 32 + t] = v;
}

// ---------------- B: bin samples by 32-word chunk -------------------------
__global__ __launch_bounds__(256) void bin_kernel(
    const int* __restrict__ sample_ids,   // [B*S]
    int* __restrict__ counts,
    int* __restrict__ list)               // [NCHUNK][CAP]
{
    const int p = blockIdx.x * 256 + threadIdx.x;   // < 163840 < 2^18
    const int w = sample_ids[p];
    const int c = w >> 5;                           // WB = 32
    const int slot = atomicAdd(&counts[c], 1);
    if (slot < CAP)
        list[c * CAP + slot] = ((w & (WB - 1)) << 18) | p;
}

// ---------------- E: stream slab (transposed) + staged serve --------------
__global__ __launch_bounds__(256) void chunk_dot_kernel(
    const float* __restrict__ outs,     // [128, NW]
    const float* __restrict__ inputs,   // [B,128]
    const int* __restrict__ counts,
    const int* __restrict__ list,
    float* __restrict__ out)            // [B*S]
{
    __shared__ float slab[WB * TS];     // [w][d] transposed, 16,896 B
    __shared__ float itile[64 * TS];    // staged input rows,  33,792 B
    const int c  = blockIdx.x;
    const int w0 = c * WB;
    const int t  = threadIdx.x;

    // phase 1: outs[d][w0..w0+31] -> slab[w][d]; 1024 f4, 4/thread.
    // global: 8 lanes x 8 f4 per row = 128B contiguous segments. NW%WB==0.
    const float4* __restrict__ outs4 = (const float4*)outs;
    #pragma unroll
    for (int i = 0; i < 4; ++i) {
        const int f4i = i * 256 + t;
        const int d = f4i >> 3;          // 0..127
        const int u = f4i & 7;           // f4 slot along w
        float4 v = outs4[((long)d * NW + w0 + 4 * u) >> 2];
        slab[(4 * u + 0) * TS + d] = v.x;
        slab[(4 * u + 1) * TS + d] = v.y;
        slab[(4 * u + 2) * TS + d] = v.z;
        slab[(4 * u + 3) * TS + d] = v.w;
    }

    const int cnt = min(counts[c], CAP);
    const float4* __restrict__ in4 = (const float4*)inputs;
    float4* itile4 = (float4*)itile;
    const float4* slab4 = (const float4*)slab;

    for (int g0 = 0; g0 < cnt; g0 += 64) {
        __syncthreads();   // slab ready (g0=0); itile free again (g0>0)
        // stage <=64 input rows: 8 lanes per row, coalesced 128B segments
        #pragma unroll
        for (int rb = 0; rb < 64; rb += 32) {
            const int rl = rb + (t >> 3);        // local row 0..63
            const int q  = t & 7;
            const int i  = g0 + rl;
            if (i < cnt) {
                const int e = list[c * CAP + i];
                const unsigned b = (unsigned)(e & 0x3FFFF) / NSAMP;
                #pragma unroll
                for (int k = 0; k < 4; ++k)
                    itile4[33 * rl + 8 * k + q] = in4[(long)b * 32 + 8 * k + q];
            }
        }
        __syncthreads();
        // compute: 4 threads per sample, 32 dims each, 2-step shfl reduce
        const int i   = g0 + (t >> 2);
        const int seg = t & 3;
        if (i < cnt) {
            const int e  = list[c * CAP + i];
            const int p  = e & 0x3FFFF;
            const int j  = e >> 18;
            const int rl = (t >> 2);             // == i - g0
            float ax = 0.f, ay = 0.f, az = 0.f, aw = 0.f;
            #pragma unroll
            for (int k = 0; k < 8; ++k) {
                float4 a = itile4[33 * rl + 8 * seg + k];
                float4 o = slab4 [33 * j  + 8 * seg + k];
                ax += a.x * o.x; ay += a.y * o.y;
                az += a.z * o.z; aw += a.w * o.w;
            }
            float s = (ax + ay) + (az + aw);
            s += __shfl_xor(s, 1, 64);           // partners stay in quad
            s += __shfl_xor(s, 2, 64);
            if (seg == 0) out[p] = s;
        }
    }
}

// ---------------- fallback (tiny ws): direct strided gather ---------------
__global__ __launch_bounds__(128) void dm_fwd_direct(
    const int* __restrict__ doc_ids,
    const int* __restrict__ context_ids,
    const int* __restrict__ sample_ids,
    const float* __restrict__ P,
    const float* __restrict__ W,
    const float* __restrict__ outs,
    float* __restrict__ out)
{
    const int b = blockIdx.x;
    const int d = threadIdx.x;
    const int lane = d & 63;
    const int wave = d >> 6;

    float v = P[(long)doc_ids[b] * VEC_DIM + d];
    #pragma unroll
    for (int c = 0; c < CTX; ++c)
        v += W[(long)context_ids[b * CTX + c] * VEC_DIM + d];

    __shared__ float partial[2 * NSAMP];
    #pragma unroll
    for (int s = 0; s < NSAMP; ++s) {
        const int w = sample_ids[b * NSAMP + s];
        float p = v * outs[(long)d * NW + w];
        #pragma unroll
        for (int off = 32; off > 0; off >>= 1)
            p += __shfl_down(p, off, 64);
        if (lane == 0) partial[wave * NSAMP + s] = p;
    }
    __syncthreads();
    if (d < NSAMP) out[b * NSAMP + d] = partial[d] + partial[NSAMP + d];
}

extern "C" void kernel_launch(void* const* d_in, const int* in_sizes, int n_in,
                              void* d_out, int out_size, void* d_ws, size_t ws_size,
                              hipStream_t stream) {
    const int*   doc_ids     = (const int*)d_in[0];
    const int*   context_ids = (const int*)d_in[1];
    const int*   sample_ids  = (const int*)d_in[2];
    const float* P           = (const float*)d_in[3];
    const float* W           = (const float*)d_in[4];
    const float* outs        = (const float*)d_in[5];
    float*       out         = (float*)d_out;

    const int B = in_sizes[0];          // 16384
    const int n_samples = B * NSAMP;    // 163840

    const size_t off_inputs = 0;
    const size_t sz_inputs  = (size_t)B * VEC_DIM * sizeof(float);   // 8.4 MB
    const size_t off_counts = off_inputs + sz_inputs;
    const size_t sz_counts  = 16384;                                 // >= NCHUNK*4
    const size_t off_list   = off_counts + sz_counts;
    const size_t sz_list    = (size_t)NCHUNK * CAP * sizeof(int);    // 3.2 MB
    const size_t needed     = off_list + sz_list;

    if (ws_size >= needed) {
        float* inputs = (float*)((char*)d_ws + off_inputs);
        int*   counts = (int*)  ((char*)d_ws + off_counts);
        int*   list   = (int*)  ((char*)d_ws + off_list);

        hipMemsetAsync(counts, 0, NCHUNK * sizeof(int), stream);
        build_inputs_kernel<<<B / 8, 256, 0, stream>>>(
            doc_ids, context_ids, P, W, inputs);
        bin_kernel<<<n_samples / 256, 256, 0, stream>>>(
            sample_ids, counts, list);
        chunk_dot_kernel<<<NCHUNK, 256, 0, stream>>>(
            outs, inputs, counts, list, out);
    } else {
        dm_fwd_direct<<<B, 128, 0, stream>>>(doc_ids, context_ids, sample_ids,
                                             P, W, outs, out);
    }
}

// Round 5
// 43.837 us; speedup vs baseline: 2.1695x; 1.4492x over previous
//
#include <hip/hip_runtime.h>

// DistributedMemory forward:
//   inputs[b,:] = P[doc_ids[b],:] + sum_c W[context_ids[b,c],:]      [B,128]
//   out[b,s]    = dot(inputs[b,:], outputs[:, sample_ids[b,s]])      [B,S]
// B=16384, C=8, S=10, D=128, N_WORDS=100000, N_DOCS=1e6. All f32.
//
// R4 -> R5: binned structure abandoned (structurally latency-bound, 63.5 vs
// 43.3 µs for plain transpose+gather). Back to R2's two-kernel shape with
// the transpose fully float4-vectorized on both the global read and global
// write side (R2's was scalar 4B = Guideline-13 violation on a pure
// streaming kernel).

#define VEC_DIM 128
#define NW      100000
#define NW4     (NW / 4)         // 25000
#define CTX     8
#define NSAMP   10
#define TWB     32               // words per transpose tile (NW % 32 == 0)
#define TS      132              // LDS row stride in floats (16B-aligned)

// -------- transpose: outs[128, NW] -> outsT[NW, 128], float4 both sides ---
__global__ __launch_bounds__(256) void transpose_kernel(
    const float* __restrict__ in,   // [128, NW]
    float* __restrict__ outT)       // [NW, 128]
{
    __shared__ float tile[TWB * TS];    // [w][d], 16,896 B
    const int t  = threadIdx.x;
    const int w0 = blockIdx.x * TWB;

    const float4* __restrict__ in4 = (const float4*)in;
    // read: 128 rows x 8 f4 along words = 1024 f4, 4/thread.
    // lanes 0..7 cover one row's 128B segment; fully coalesced per segment.
    #pragma unroll
    for (int i = 0; i < 4; ++i) {
        const int f4i = i * 256 + t;
        const int d = f4i >> 3;             // 0..127
        const int u = f4i & 7;              // f4 slot along w
        float4 v = in4[d * NW4 + (w0 >> 2) + u];
        tile[(4 * u + 0) * TS + d] = v.x;
        tile[(4 * u + 1) * TS + d] = v.y;
        tile[(4 * u + 2) * TS + d] = v.z;
        tile[(4 * u + 3) * TS + d] = v.w;
    }
    __syncthreads();

    // write: 32 w-rows x 32 f4 = 1024 f4, 4/thread; 512B contiguous per row.
    float4* __restrict__ outT4 = (float4*)outT;
    const float4* tile4 = (const float4*)tile;      // row stride 33 f4
    #pragma unroll
    for (int i = 0; i < 4; ++i) {
        const int f4i = i * 256 + t;
        const int w = f4i >> 5;             // 0..31
        const int q = f4i & 31;             // f4 slot along d
        outT4[(w0 + w) * 32 + q] = tile4[w * 33 + q];
    }
}

// -------- fused: build inputs in registers + gather outsT rows + dot ------
__global__ __launch_bounds__(256) void dm_fwd_kernel(
    const int* __restrict__ doc_ids,
    const int* __restrict__ context_ids,
    const int* __restrict__ sample_ids,
    const float* __restrict__ P,       // [N_DOCS, 128]
    const float* __restrict__ W,       // [NW, 128]
    const float* __restrict__ outsT,   // [NW, 128]
    float* __restrict__ out)           // [B, S]
{
    const int t = threadIdx.x & 31;                      // lane in sub-group
    const int b = blockIdx.x * 8 + (threadIdx.x >> 5);   // batch element

    const float4* __restrict__ P4 = (const float4*)P;
    const float4* __restrict__ W4 = (const float4*)W;
    const float4* __restrict__ O4 = (const float4*)outsT;

    // all f4 indices fit in 32-bit (max 1e6*32 = 3.2e7)
    float4 v = P4[doc_ids[b] * 32 + t];
    #pragma unroll
    for (int c = 0; c < CTX; ++c) {
        float4 w4 = W4[context_ids[b * CTX + c] * 32 + t];
        v.x += w4.x; v.y += w4.y; v.z += w4.z; v.w += w4.w;
    }

    int wids[NSAMP];
    #pragma unroll
    for (int s = 0; s < NSAMP; ++s) wids[s] = sample_ids[b * NSAMP + s];

    #pragma unroll
    for (int s = 0; s < NSAMP; ++s) {
        float4 o = O4[wids[s] * 32 + t];                 // 512B contiguous
        float p = v.x * o.x + v.y * o.y + v.z * o.z + v.w * o.w;
        #pragma unroll
        for (int off = 16; off > 0; off >>= 1)
            p += __shfl_down(p, off, 32);
        if (t == 0) out[b * NSAMP + s] = p;
    }
}

// -------- fallback (tiny ws): direct strided gather ----------------------
__global__ __launch_bounds__(128) void dm_fwd_direct(
    const int* __restrict__ doc_ids,
    const int* __restrict__ context_ids,
    const int* __restrict__ sample_ids,
    const float* __restrict__ P,
    const float* __restrict__ W,
    const float* __restrict__ outs,    // [128, NW]
    float* __restrict__ out)
{
    const int b = blockIdx.x;
    const int d = threadIdx.x;
    const int lane = d & 63;
    const int wave = d >> 6;

    float v = P[(long)doc_ids[b] * VEC_DIM + d];
    #pragma unroll
    for (int c = 0; c < CTX; ++c)
        v += W[(long)context_ids[b * CTX + c] * VEC_DIM + d];

    __shared__ float partial[2 * NSAMP];
    #pragma unroll
    for (int s = 0; s < NSAMP; ++s) {
        const int w = sample_ids[b * NSAMP + s];
        float p = v * outs[(long)d * NW + w];
        #pragma unroll
        for (int off = 32; off > 0; off >>= 1)
            p += __shfl_down(p, off, 64);
        if (lane == 0) partial[wave * NSAMP + s] = p;
    }
    __syncthreads();
    if (d < NSAMP) out[b * NSAMP + d] = partial[d] + partial[NSAMP + d];
}

extern "C" void kernel_launch(void* const* d_in, const int* in_sizes, int n_in,
                              void* d_out, int out_size, void* d_ws, size_t ws_size,
                              hipStream_t stream) {
    const int*   doc_ids     = (const int*)d_in[0];
    const int*   context_ids = (const int*)d_in[1];
    const int*   sample_ids  = (const int*)d_in[2];
    const float* P           = (const float*)d_in[3];
    const float* W           = (const float*)d_in[4];
    const float* outs        = (const float*)d_in[5];
    float*       out         = (float*)d_out;

    const int B = in_sizes[0];  // 16384
    const size_t needed = (size_t)NW * VEC_DIM * sizeof(float);  // 51.2 MB

    if (ws_size >= needed) {
        float* outsT = (float*)d_ws;
        transpose_kernel<<<NW / TWB, 256, 0, stream>>>(outs, outsT);
        dm_fwd_kernel<<<B / 8, 256, 0, stream>>>(doc_ids, context_ids, sample_ids,
                                                 P, W, outsT, out);
    } else {
        dm_fwd_direct<<<B, 128, 0, stream>>>(doc_ids, context_ids, sample_ids,
                                             P, W, outs, out);
    }
}